// Round 9
// baseline (202.135 us; speedup 1.0000x reference)
//
#include <hip/hip_runtime.h>
#include <math.h>

#define NN 10000
#define NE 160000
#define CAP 96   // per-node edge bin capacity; deg ~ Poisson(16), +20 sigma
// Only the l=0 irrep reaches the output (scal takes cols h*72..h*72+8 of pooled,
// which come solely from node_out[:,:,0]; Y[:,0]==1). l=1/l=2 paths are dead.
//
// Round 9: R8's PWL collapse with the binary-search off-by-one fixed.
// R8 bug: steps {32..1} cap kk at 63; with b1==0 every tau==0 and every edge
// needs kk==64 -> one relu unit dropped per head per edge (absmax 19).
// Steps {64,32,...,1} reach all counts 0..64.
//
// Workspace (floats):
//   x      [10000][16]        @ 0
//   q      [10000][2][16]
//   k      [10000][2][16]
//   feat   [10000][16]
//   pooled [16][16]
//   deg    int[10000]          (pooled..deg zeroed together in k_xqk)
//   sTau   [2][64]             sorted breakpoints
//   gT     [2][65][36]         PWL table: [0..15]=A_c,[16]=Aatt,[17]=Batt,[20..35]=B_c
//   lgp    [10000][96][2]      fp32 logits
//   gb     [10000][96][2][4]   uint, bf16x2-packed g[8] per head

__device__ __forceinline__ unsigned bf16pack2(float a, float b) {
    unsigned ua = __float_as_uint(a);
    unsigned ub = __float_as_uint(b);
    ua = ua + 0x7fffu + ((ua >> 16) & 1u);
    ub = ub + 0x7fffu + ((ub >> 16) & 1u);
    return (ua >> 16) | (ub & 0xffff0000u);
}

// x = nf @ We + be ; q[h] = x @ Wq[h] ; k[h] = x @ Wk[h]; zeroes pooled+deg
__global__ __launch_bounds__(256) void k_xqk(const float* __restrict__ nf,
        const float* __restrict__ We, const float* __restrict__ be,
        const float* __restrict__ Wq, const float* __restrict__ Wk,
        float* __restrict__ x, float* __restrict__ q, float* __restrict__ k,
        int* __restrict__ zeroReg) {
    int t = threadIdx.x;
    int gid = blockIdx.x * 256 + t;
    if (gid < 10256) zeroReg[gid] = 0;   // pooled(256f)+deg(10000i), contiguous
    __shared__ float sWe[64 * 16];
    __shared__ float sWq[2 * 16 * 16];
    __shared__ float sWk[2 * 16 * 16];
    __shared__ float sNF[16 * 64];
    __shared__ float sX[16 * 16];
    for (int i = t; i < 1024; i += 256) sWe[i] = We[i];
    for (int i = t; i < 512; i += 256) { sWq[i] = Wq[i]; sWk[i] = Wk[i]; }
    int nodeBase = blockIdx.x * 16;
    for (int i = t; i < 1024; i += 256) {
        int n = nodeBase + (i >> 6);
        sNF[i] = (n < NN) ? nf[n * 64 + (i & 63)] : 0.0f;
    }
    __syncthreads();
    int ln = t >> 4, c = t & 15;
    int n = nodeBase + ln;
    float acc = be[c];
    #pragma unroll 16
    for (int j = 0; j < 64; ++j) acc = fmaf(sNF[ln * 64 + j], sWe[j * 16 + c], acc);
    sX[ln * 16 + c] = acc;
    __syncthreads();
    if (n < NN) {
        x[n * 16 + c] = acc;
        #pragma unroll
        for (int h = 0; h < 2; ++h) {
            float aq = 0.0f, ak = 0.0f;
            #pragma unroll
            for (int j = 0; j < 16; ++j) {
                float xv = sX[ln * 16 + j];
                aq = fmaf(xv, sWq[(h * 16 + j) * 16 + c], aq);
                ak = fmaf(xv, sWk[(h * 16 + j) * 16 + c], ak);
            }
            q[(n * 2 + h) * 16 + c] = aq;
            k[(n * 2 + h) * 16 + c] = ak;
        }
    }
}

// one block: build sorted breakpoints + PWL interval table per head.
__global__ __launch_bounds__(256) void k_prep(const float* __restrict__ W1,
        const float* __restrict__ b1, const float* __restrict__ Wa,
        const float* __restrict__ Wv,
        float* __restrict__ sTau, float* __restrict__ gT) {
    __shared__ float sW[128], sB[128], sA[128], sT[128];
    __shared__ int sRank[128];
    int t = threadIdx.x;
    if (t < 128) { sW[t] = W1[t]; sB[t] = b1[t]; sA[t] = Wa[t]; }
    __syncthreads();
    if (t < 128) {
        float w = sW[t], b = sB[t];
        // w==0: b>0 -> always active (tau=-inf); b<=0 -> never (tau=+inf); both pos-slope class
        float tau = (w != 0.0f) ? (-b / w) : ((b > 0.0f) ? -INFINITY : INFINITY);
        sT[t] = tau;
    }
    __syncthreads();
    if (t < 128) {
        int h = t >> 6, j = t & 63;
        float tau = sT[t];
        int r = 0;
        for (int jj = 0; jj < 64; ++jj) {
            float o = sT[h * 64 + jj];
            r += (o < tau) || (o == tau && jj < j);
        }
        sRank[t] = r;
        sTau[h * 64 + r] = tau;
    }
    __syncthreads();
    // 2210 entries: h, k in [0,64], c in [0,16]
    for (int idx = t; idx < 2210; idx += 256) {
        int h = idx / 1105;
        int rem = idx - h * 1105;
        int k = rem / 17;
        int c = rem - k * 17;
        float A = 0.0f, B = 0.0f;
        for (int j = 0; j < 64; ++j) {
            int jj = h * 64 + j;
            float w = sW[jj], b = sB[jj];
            bool posSlope = (w >= 0.0f);
            int r = sRank[jj];
            bool active = posSlope ? (r < k) : (r >= k);
            if (active) {
                float v = (c < 16) ? Wv[jj * 48 + 3 * c] : sA[jj];
                A = fmaf(w, v, A);
                B = fmaf(b, v, B);
            }
        }
        float* row = gT + (h * 65 + k) * 36;
        if (c < 16) { row[c] = A; row[20 + c] = B; }
        else        { row[16] = A; row[17] = B; }
    }
}

// one thread per edge: PWL-evaluated logits + g[8], bin slot tgt*CAP+p.
__global__ __launch_bounds__(256) void k_edge(const float* __restrict__ pos,
        const int* __restrict__ ei,
        const float* __restrict__ q, const float* __restrict__ k,
        const float* __restrict__ sTau, const float* __restrict__ gT,
        const float* __restrict__ Wo,
        const float* __restrict__ x, int* __restrict__ deg,
        float* __restrict__ lgp, uint4* __restrict__ gb) {
    int e = blockIdx.x * 256 + threadIdx.x;
    if (e >= NE) return;
    int s = ei[e], t = ei[NE + e];
    int p = atomicAdd(&deg[t], 1);
    bool ok = (p < CAP);
    size_t slot = (size_t)t * CAP + p;
    float dx = pos[t * 3 + 0] - pos[s * 3 + 0];
    float dy = pos[t * 3 + 1] - pos[s * 3 + 1];
    float dz = pos[t * 3 + 2] - pos[s * 3 + 2];
    float d = sqrtf(dx * dx + dy * dy + dz * dz);
    float fh[2] = { d, 1.0f / (d * d) };
    const float4* xp = (const float4*)(x + (size_t)s * 16);
    float4 xs0 = xp[0], xs1 = xp[1], xs2 = xp[2], xs3 = xp[3];
    float xf[16] = { xs0.x, xs0.y, xs0.z, xs0.w, xs1.x, xs1.y, xs1.z, xs1.w,
                     xs2.x, xs2.y, xs2.z, xs2.w, xs3.x, xs3.y, xs3.z, xs3.w };
    float L2v[2];
    #pragma unroll
    for (int h = 0; h < 2; ++h) {
        const float4* qt = (const float4*)(q + (size_t)t * 32 + h * 16);
        const float4* ks = (const float4*)(k + (size_t)s * 32 + h * 16);
        float4 a0 = qt[0], a1 = qt[1], a2 = qt[2], a3 = qt[3];
        float4 b0 = ks[0], c1 = ks[1], c2 = ks[2], c3 = ks[3];
        float dot = a0.x * b0.x + a0.y * b0.y + a0.z * b0.z + a0.w * b0.w
                  + a1.x * c1.x + a1.y * c1.y + a1.z * c1.z + a1.w * c1.w
                  + a2.x * c2.x + a2.y * c2.y + a2.z * c2.z + a2.w * c2.w
                  + a3.x * c3.x + a3.y * c3.y + a3.z * c3.z + a3.w * c3.w;
        float f = fh[h];
        // kk = #{tau <= f} in sorted sTau[h][0..63]; steps {64..1} reach 0..64
        const float* tb = sTau + h * 64;
        int kk = 0;
        #pragma unroll
        for (int step = 64; step >= 1; step >>= 1) {
            int mid = kk + step;
            if (mid <= 64 && tb[mid - 1] <= f) kk = mid;
        }
        const float* row = gT + (h * 65 + kk) * 36;
        float4 A0 = *(const float4*)(row + 0);
        float4 A1 = *(const float4*)(row + 4);
        float4 A2 = *(const float4*)(row + 8);
        float4 A3 = *(const float4*)(row + 12);
        float2 AB = *(const float2*)(row + 16);
        float4 B0 = *(const float4*)(row + 20);
        float4 B1 = *(const float4*)(row + 24);
        float4 B2 = *(const float4*)(row + 28);
        float4 B3 = *(const float4*)(row + 32);
        L2v[h] = fmaf(dot, 0.25f, fmaf(AB.x, f, AB.y));
        float acc[16] = {
            fmaf(A0.x, f, B0.x), fmaf(A0.y, f, B0.y), fmaf(A0.z, f, B0.z), fmaf(A0.w, f, B0.w),
            fmaf(A1.x, f, B1.x), fmaf(A1.y, f, B1.y), fmaf(A1.z, f, B1.z), fmaf(A1.w, f, B1.w),
            fmaf(A2.x, f, B2.x), fmaf(A2.y, f, B2.y), fmaf(A2.z, f, B2.z), fmaf(A2.w, f, B2.w),
            fmaf(A3.x, f, B3.x), fmaf(A3.y, f, B3.y), fmaf(A3.z, f, B3.z), fmaf(A3.w, f, B3.w) };
        float g[8] = {0,0,0,0,0,0,0,0};
        const float* wob = Wo + h * 384;   // Wo[h][0][c][o], uniform scalars
        #pragma unroll
        for (int c = 0; c < 16; ++c) {
            float axc = acc[c] * xf[c];
            #pragma unroll
            for (int o = 0; o < 8; ++o) g[o] = fmaf(axc, wob[c * 8 + o], g[o]);
        }
        if (ok) {
            gb[slot * 2 + h] = make_uint4(bf16pack2(g[0], g[1]), bf16pack2(g[2], g[3]),
                                          bf16pack2(g[4], g[5]), bf16pack2(g[6], g[7]));
        }
    }
    if (ok) *(float2*)(lgp + slot * 2) = make_float2(L2v[0], L2v[1]);
}

// wave per (node,head): 16 edge-groups x 4 lanes x 2 outputs (bf16x2 unpack),
// single-pass online softmax, -inf-safe merges.
__global__ __launch_bounds__(256) void k_gather(const int* __restrict__ deg,
        const float* __restrict__ lgp, const unsigned* __restrict__ gb,
        float* __restrict__ feat) {
    int t0 = threadIdx.x;
    int wv = t0 >> 6;
    int lane = t0 & 63;
    int pid = blockIdx.x * 4 + wv;        // (node,head) pair; grid exact
    int n = pid >> 1, h = pid & 1;
    int dg = min(deg[n], CAP);
    int g = lane >> 2, p = lane & 3;      // group 0..15, uint index 0..3
    float m = -INFINITY, z = 0.0f, u0 = 0.0f, u1 = 0.0f;
    const float* lgb = lgp + (size_t)n * (CAP * 2) + h;
    const unsigned* gbb = gb + (size_t)n * (CAP * 8) + h * 4 + p;
    for (int i = g; i < dg; i += 16) {
        float L = lgb[i * 2];
        unsigned wbits = gbb[(size_t)i * 8];
        float ga = __uint_as_float(wbits << 16);
        float gbv = __uint_as_float(wbits & 0xffff0000u);
        float nm = fmaxf(m, L);
        float sc = (m > -INFINITY) ? __expf(m - nm) : 0.0f;
        float w  = __expf(L - nm);
        u0 = fmaf(u0, sc, w * ga);
        u1 = fmaf(u1, sc, w * gbv);
        z  = fmaf(z, sc, w);
        m = nm;
    }
    #pragma unroll
    for (int off = 4; off <= 32; off <<= 1) {
        float mo = __shfl_xor(m, off, 64);
        float zo = __shfl_xor(z, off, 64);
        float a0o = __shfl_xor(u0, off, 64);
        float a1o = __shfl_xor(u1, off, 64);
        float nm = fmaxf(m, mo);
        float a = (m  > -INFINITY) ? __expf(m  - nm) : 0.0f;
        float b = (mo > -INFINITY) ? __expf(mo - nm) : 0.0f;
        u0 = u0 * a + a0o * b;
        u1 = u1 * a + a1o * b;
        z  = z * a + zo * b;
        m = nm;
    }
    if (lane < 4) {
        float inv = (z > 0.0f) ? 1.0f / z : 0.0f;
        *(float2*)(feat + n * 16 + h * 8 + p * 2) = make_float2(u0 * inv, u1 * inv);
    }
}

// pooled[g][hc] += feat[n][hc]; run-length accumulation (batch sorted).
__global__ __launch_bounds__(256) void k_pool(const float* __restrict__ feat,
        const int* __restrict__ batch, float* __restrict__ pooled) {
    __shared__ float sP[256];
    int t = threadIdx.x;
    sP[t] = 0.0f;
    __syncthreads();
    int tid = blockIdx.x * 256 + t;        // 0..10239
    int c = tid & 15, seg = tid >> 4;      // seg 0..639
    int n0 = seg * 16, n1 = min(n0 + 16, NN);
    float run = 0.0f;
    int curg = -1;
    for (int n = n0; n < n1; ++n) {
        int gg = batch[n];
        if (gg != curg) {
            if (curg >= 0) atomicAdd(&sP[curg * 16 + c], run);
            run = 0.0f; curg = gg;
        }
        run += feat[n * 16 + c];
    }
    if (curg >= 0) atomicAdd(&sP[curg * 16 + c], run);
    __syncthreads();
    atomicAdd(&pooled[t], sP[t]);
}

__global__ __launch_bounds__(512) void k_final(const float* __restrict__ pooled,
        const float* __restrict__ Wproj, const float* __restrict__ bproj,
        float* __restrict__ out) {
    int t = threadIdx.x;
    int g = t >> 5, fo = t & 31;
    float acc = bproj[fo];
    #pragma unroll
    for (int j = 0; j < 16; ++j) acc = fmaf(pooled[g * 16 + j], Wproj[j * 32 + fo], acc);
    out[g * 32 + fo] = acc;
}

extern "C" void kernel_launch(void* const* d_in, const int* in_sizes, int n_in,
                              void* d_out, int out_size, void* d_ws, size_t ws_size,
                              hipStream_t stream) {
    const float* nf    = (const float*)d_in[0];
    const float* pos   = (const float*)d_in[1];
    const float* We    = (const float*)d_in[2];
    const float* be    = (const float*)d_in[3];
    const float* Wq    = (const float*)d_in[4];
    const float* Wk    = (const float*)d_in[5];
    const float* W1    = (const float*)d_in[6];
    const float* b1    = (const float*)d_in[7];
    const float* Wa    = (const float*)d_in[8];
    const float* Wv    = (const float*)d_in[9];
    const float* Wo    = (const float*)d_in[10];
    const float* Wproj = (const float*)d_in[11];
    const float* bproj = (const float*)d_in[12];
    const int*   ei    = (const int*)d_in[13];
    const int*   batch = (const int*)d_in[14];
    float* out = (float*)d_out;
    (void)in_sizes; (void)n_in; (void)out_size; (void)ws_size;

    float* ws     = (float*)d_ws;
    float* x      = ws;                  // 160000
    float* q      = x + 160000;          // 320000
    float* k      = q + 320000;          // 320000
    float* feat   = k + 320000;          // 160000
    float* pooled = feat + 160000;       // 256
    int*   deg    = (int*)(pooled + 256);// 10000
    float* sTau   = (float*)(deg + 10000);   // 128
    float* gT     = sTau + 128;              // 4680
    float* lgp    = gT + 4680;               // 1,920,000
    unsigned* gbu = (unsigned*)(lgp + (size_t)NN * CAP * 2);  // 7,680,000 (16B-aligned)

    hipLaunchKernelGGL(k_xqk,    dim3(625),  dim3(256), 0, stream, nf, We, be, Wq, Wk, x, q, k, (int*)pooled);
    hipLaunchKernelGGL(k_prep,   dim3(1),    dim3(256), 0, stream, W1, b1, Wa, Wv, sTau, gT);
    hipLaunchKernelGGL(k_edge,   dim3(625),  dim3(256), 0, stream, pos, ei, q, k, sTau, gT, Wo, x, deg, lgp, (uint4*)gbu);
    hipLaunchKernelGGL(k_gather, dim3(5000), dim3(256), 0, stream, deg, lgp, gbu, feat);
    hipLaunchKernelGGL(k_pool,   dim3(40),   dim3(256), 0, stream, feat, batch, pooled);
    hipLaunchKernelGGL(k_final,  dim3(1),    dim3(512), 0, stream, pooled, Wproj, bproj, out);
}

// Round 10
// 136.511 us; speedup vs baseline: 1.4807x; 1.4807x over previous
//
#include <hip/hip_runtime.h>
#include <math.h>

#define NN 10000
#define NE 160000
#define CAP 96   // per-node edge bin capacity; deg ~ Poisson(16), +20 sigma
// Only the l=0 irrep reaches the output (scal takes cols h*72..h*72+8 of pooled,
// which come solely from node_out[:,:,0]; Y[:,0]==1). l=1/l=2 paths are dead.
//
// Round 10: R9 was correct but k_prep (1 block) took 80-90 us — serial
// prologue, 576 scattered Wv loads on one CU. Now 9 blocks: each block
// redundantly computes tau/ranks in LDS, stages Wv[:, ::3] into LDS
// coalesced, and builds 256 of the 2210 PWL-table entries.
//
// Workspace (floats):
//   x      [10000][16]        @ 0
//   q      [10000][2][16]
//   k      [10000][2][16]
//   feat   [10000][16]
//   pooled [16][16]
//   deg    int[10000]          (pooled..deg zeroed together in k_xqk)
//   sTau   [2][64]             sorted breakpoints
//   gT     [2][65][36]         PWL table: [0..15]=A_c,[16]=Aatt,[17]=Batt,[20..35]=B_c
//   lgp    [10000][96][2]      fp32 logits
//   gb     [10000][96][2][4]   uint, bf16x2-packed g[8] per head

__device__ __forceinline__ unsigned bf16pack2(float a, float b) {
    unsigned ua = __float_as_uint(a);
    unsigned ub = __float_as_uint(b);
    ua = ua + 0x7fffu + ((ua >> 16) & 1u);
    ub = ub + 0x7fffu + ((ub >> 16) & 1u);
    return (ua >> 16) | (ub & 0xffff0000u);
}

// x = nf @ We + be ; q[h] = x @ Wq[h] ; k[h] = x @ Wk[h]; zeroes pooled+deg
__global__ __launch_bounds__(256) void k_xqk(const float* __restrict__ nf,
        const float* __restrict__ We, const float* __restrict__ be,
        const float* __restrict__ Wq, const float* __restrict__ Wk,
        float* __restrict__ x, float* __restrict__ q, float* __restrict__ k,
        int* __restrict__ zeroReg) {
    int t = threadIdx.x;
    int gid = blockIdx.x * 256 + t;
    if (gid < 10256) zeroReg[gid] = 0;   // pooled(256f)+deg(10000i), contiguous
    __shared__ float sWe[64 * 16];
    __shared__ float sWq[2 * 16 * 16];
    __shared__ float sWk[2 * 16 * 16];
    __shared__ float sNF[16 * 64];
    __shared__ float sX[16 * 16];
    for (int i = t; i < 1024; i += 256) sWe[i] = We[i];
    for (int i = t; i < 512; i += 256) { sWq[i] = Wq[i]; sWk[i] = Wk[i]; }
    int nodeBase = blockIdx.x * 16;
    for (int i = t; i < 1024; i += 256) {
        int n = nodeBase + (i >> 6);
        sNF[i] = (n < NN) ? nf[n * 64 + (i & 63)] : 0.0f;
    }
    __syncthreads();
    int ln = t >> 4, c = t & 15;
    int n = nodeBase + ln;
    float acc = be[c];
    #pragma unroll 16
    for (int j = 0; j < 64; ++j) acc = fmaf(sNF[ln * 64 + j], sWe[j * 16 + c], acc);
    sX[ln * 16 + c] = acc;
    __syncthreads();
    if (n < NN) {
        x[n * 16 + c] = acc;
        #pragma unroll
        for (int h = 0; h < 2; ++h) {
            float aq = 0.0f, ak = 0.0f;
            #pragma unroll
            for (int j = 0; j < 16; ++j) {
                float xv = sX[ln * 16 + j];
                aq = fmaf(xv, sWq[(h * 16 + j) * 16 + c], aq);
                ak = fmaf(xv, sWk[(h * 16 + j) * 16 + c], ak);
            }
            q[(n * 2 + h) * 16 + c] = aq;
            k[(n * 2 + h) * 16 + c] = ak;
        }
    }
}

// 9 blocks: build sorted breakpoints + PWL interval table per head.
// Each block redundantly computes tau/rank (cheap, LDS) and stages the
// compacted Wv into LDS; each thread then builds one table entry.
__global__ __launch_bounds__(256) void k_prep(const float* __restrict__ W1,
        const float* __restrict__ b1, const float* __restrict__ Wa,
        const float* __restrict__ Wv,
        float* __restrict__ sTau, float* __restrict__ gT) {
    __shared__ float sW[128], sB[128], sA[128], sT[128];
    __shared__ float sV[2048];   // [h][j][c] compacted Wv[:, ::3]
    __shared__ int sRank[128];
    int t = threadIdx.x;
    if (t < 128) { sW[t] = W1[t]; sB[t] = b1[t]; sA[t] = Wa[t]; }
    for (int i = t; i < 2048; i += 256) {
        int h = i >> 10, j = (i >> 4) & 63, c = i & 15;
        sV[i] = Wv[(h * 64 + j) * 48 + 3 * c];
    }
    __syncthreads();
    if (t < 128) {
        float w = sW[t], b = sB[t];
        // w==0: b>0 -> always active (tau=-inf); b<=0 -> never (tau=+inf)
        sT[t] = (w != 0.0f) ? (-b / w) : ((b > 0.0f) ? -INFINITY : INFINITY);
    }
    __syncthreads();
    if (t < 128) {
        int h = t >> 6, j = t & 63;
        float tau = sT[t];
        int r = 0;
        for (int jj = 0; jj < 64; ++jj) {
            float o = sT[h * 64 + jj];
            r += (o < tau) || (o == tau && jj < j);
        }
        sRank[t] = r;
        if (blockIdx.x == 0) sTau[h * 64 + r] = tau;
    }
    __syncthreads();
    int idx = blockIdx.x * 256 + t;      // 2210 entries: h, k in [0,64], c in [0,16]
    if (idx < 2210) {
        int h = idx / 1105;
        int rem = idx - h * 1105;
        int k = rem / 17;
        int c = rem - k * 17;
        float A = 0.0f, B = 0.0f;
        for (int j = 0; j < 64; ++j) {
            int jj = h * 64 + j;
            float w = sW[jj], b = sB[jj];
            bool posSlope = (w >= 0.0f);
            int r = sRank[jj];
            bool active = posSlope ? (r < k) : (r >= k);
            if (active) {
                float v = (c < 16) ? sV[h * 1024 + j * 16 + c] : sA[jj];
                A = fmaf(w, v, A);
                B = fmaf(b, v, B);
            }
        }
        float* row = gT + (h * 65 + k) * 36;
        if (c < 16) { row[c] = A; row[20 + c] = B; }
        else        { row[16] = A; row[17] = B; }
    }
}

// one thread per edge: PWL-evaluated logits + g[8], bin slot tgt*CAP+p.
__global__ __launch_bounds__(256) void k_edge(const float* __restrict__ pos,
        const int* __restrict__ ei,
        const float* __restrict__ q, const float* __restrict__ k,
        const float* __restrict__ sTau, const float* __restrict__ gT,
        const float* __restrict__ Wo,
        const float* __restrict__ x, int* __restrict__ deg,
        float* __restrict__ lgp, uint4* __restrict__ gb) {
    int e = blockIdx.x * 256 + threadIdx.x;
    if (e >= NE) return;
    int s = ei[e], t = ei[NE + e];
    int p = atomicAdd(&deg[t], 1);
    bool ok = (p < CAP);
    size_t slot = (size_t)t * CAP + p;
    float dx = pos[t * 3 + 0] - pos[s * 3 + 0];
    float dy = pos[t * 3 + 1] - pos[s * 3 + 1];
    float dz = pos[t * 3 + 2] - pos[s * 3 + 2];
    float d = sqrtf(dx * dx + dy * dy + dz * dz);
    float fh[2] = { d, 1.0f / (d * d) };
    const float4* xp = (const float4*)(x + (size_t)s * 16);
    float4 xs0 = xp[0], xs1 = xp[1], xs2 = xp[2], xs3 = xp[3];
    float xf[16] = { xs0.x, xs0.y, xs0.z, xs0.w, xs1.x, xs1.y, xs1.z, xs1.w,
                     xs2.x, xs2.y, xs2.z, xs2.w, xs3.x, xs3.y, xs3.z, xs3.w };
    float L2v[2];
    #pragma unroll
    for (int h = 0; h < 2; ++h) {
        const float4* qt = (const float4*)(q + (size_t)t * 32 + h * 16);
        const float4* ks = (const float4*)(k + (size_t)s * 32 + h * 16);
        float4 a0 = qt[0], a1 = qt[1], a2 = qt[2], a3 = qt[3];
        float4 b0 = ks[0], c1 = ks[1], c2 = ks[2], c3 = ks[3];
        float dot = a0.x * b0.x + a0.y * b0.y + a0.z * b0.z + a0.w * b0.w
                  + a1.x * c1.x + a1.y * c1.y + a1.z * c1.z + a1.w * c1.w
                  + a2.x * c2.x + a2.y * c2.y + a2.z * c2.z + a2.w * c2.w
                  + a3.x * c3.x + a3.y * c3.y + a3.z * c3.z + a3.w * c3.w;
        float f = fh[h];
        // kk = #{tau <= f} in sorted sTau[h][0..63]; steps {64..1} reach 0..64
        const float* tb = sTau + h * 64;
        int kk = 0;
        #pragma unroll
        for (int step = 64; step >= 1; step >>= 1) {
            int mid = kk + step;
            if (mid <= 64 && tb[mid - 1] <= f) kk = mid;
        }
        const float* row = gT + (h * 65 + kk) * 36;
        float4 A0 = *(const float4*)(row + 0);
        float4 A1 = *(const float4*)(row + 4);
        float4 A2 = *(const float4*)(row + 8);
        float4 A3 = *(const float4*)(row + 12);
        float2 AB = *(const float2*)(row + 16);
        float4 B0 = *(const float4*)(row + 20);
        float4 B1 = *(const float4*)(row + 24);
        float4 B2 = *(const float4*)(row + 28);
        float4 B3 = *(const float4*)(row + 32);
        L2v[h] = fmaf(dot, 0.25f, fmaf(AB.x, f, AB.y));
        float acc[16] = {
            fmaf(A0.x, f, B0.x), fmaf(A0.y, f, B0.y), fmaf(A0.z, f, B0.z), fmaf(A0.w, f, B0.w),
            fmaf(A1.x, f, B1.x), fmaf(A1.y, f, B1.y), fmaf(A1.z, f, B1.z), fmaf(A1.w, f, B1.w),
            fmaf(A2.x, f, B2.x), fmaf(A2.y, f, B2.y), fmaf(A2.z, f, B2.z), fmaf(A2.w, f, B2.w),
            fmaf(A3.x, f, B3.x), fmaf(A3.y, f, B3.y), fmaf(A3.z, f, B3.z), fmaf(A3.w, f, B3.w) };
        float g[8] = {0,0,0,0,0,0,0,0};
        const float* wob = Wo + h * 384;   // Wo[h][0][c][o], uniform scalars
        #pragma unroll
        for (int c = 0; c < 16; ++c) {
            float axc = acc[c] * xf[c];
            #pragma unroll
            for (int o = 0; o < 8; ++o) g[o] = fmaf(axc, wob[c * 8 + o], g[o]);
        }
        if (ok) {
            gb[slot * 2 + h] = make_uint4(bf16pack2(g[0], g[1]), bf16pack2(g[2], g[3]),
                                          bf16pack2(g[4], g[5]), bf16pack2(g[6], g[7]));
        }
    }
    if (ok) *(float2*)(lgp + slot * 2) = make_float2(L2v[0], L2v[1]);
}

// wave per (node,head): 16 edge-groups x 4 lanes x 2 outputs (bf16x2 unpack),
// single-pass online softmax, -inf-safe merges.
__global__ __launch_bounds__(256) void k_gather(const int* __restrict__ deg,
        const float* __restrict__ lgp, const unsigned* __restrict__ gb,
        float* __restrict__ feat) {
    int t0 = threadIdx.x;
    int wv = t0 >> 6;
    int lane = t0 & 63;
    int pid = blockIdx.x * 4 + wv;        // (node,head) pair; grid exact
    int n = pid >> 1, h = pid & 1;
    int dg = min(deg[n], CAP);
    int g = lane >> 2, p = lane & 3;      // group 0..15, uint index 0..3
    float m = -INFINITY, z = 0.0f, u0 = 0.0f, u1 = 0.0f;
    const float* lgb = lgp + (size_t)n * (CAP * 2) + h;
    const unsigned* gbb = gb + (size_t)n * (CAP * 8) + h * 4 + p;
    for (int i = g; i < dg; i += 16) {
        float L = lgb[i * 2];
        unsigned wbits = gbb[(size_t)i * 8];
        float ga = __uint_as_float(wbits << 16);
        float gbv = __uint_as_float(wbits & 0xffff0000u);
        float nm = fmaxf(m, L);
        float sc = (m > -INFINITY) ? __expf(m - nm) : 0.0f;
        float w  = __expf(L - nm);
        u0 = fmaf(u0, sc, w * ga);
        u1 = fmaf(u1, sc, w * gbv);
        z  = fmaf(z, sc, w);
        m = nm;
    }
    #pragma unroll
    for (int off = 4; off <= 32; off <<= 1) {
        float mo = __shfl_xor(m, off, 64);
        float zo = __shfl_xor(z, off, 64);
        float a0o = __shfl_xor(u0, off, 64);
        float a1o = __shfl_xor(u1, off, 64);
        float nm = fmaxf(m, mo);
        float a = (m  > -INFINITY) ? __expf(m  - nm) : 0.0f;
        float b = (mo > -INFINITY) ? __expf(mo - nm) : 0.0f;
        u0 = u0 * a + a0o * b;
        u1 = u1 * a + a1o * b;
        z  = z * a + zo * b;
        m = nm;
    }
    if (lane < 4) {
        float inv = (z > 0.0f) ? 1.0f / z : 0.0f;
        *(float2*)(feat + n * 16 + h * 8 + p * 2) = make_float2(u0 * inv, u1 * inv);
    }
}

// pooled[g][hc] += feat[n][hc]; run-length accumulation (batch sorted).
__global__ __launch_bounds__(256) void k_pool(const float* __restrict__ feat,
        const int* __restrict__ batch, float* __restrict__ pooled) {
    __shared__ float sP[256];
    int t = threadIdx.x;
    sP[t] = 0.0f;
    __syncthreads();
    int tid = blockIdx.x * 256 + t;        // 0..10239
    int c = tid & 15, seg = tid >> 4;      // seg 0..639
    int n0 = seg * 16, n1 = min(n0 + 16, NN);
    float run = 0.0f;
    int curg = -1;
    for (int n = n0; n < n1; ++n) {
        int gg = batch[n];
        if (gg != curg) {
            if (curg >= 0) atomicAdd(&sP[curg * 16 + c], run);
            run = 0.0f; curg = gg;
        }
        run += feat[n * 16 + c];
    }
    if (curg >= 0) atomicAdd(&sP[curg * 16 + c], run);
    __syncthreads();
    atomicAdd(&pooled[t], sP[t]);
}

__global__ __launch_bounds__(512) void k_final(const float* __restrict__ pooled,
        const float* __restrict__ Wproj, const float* __restrict__ bproj,
        float* __restrict__ out) {
    int t = threadIdx.x;
    int g = t >> 5, fo = t & 31;
    float acc = bproj[fo];
    #pragma unroll
    for (int j = 0; j < 16; ++j) acc = fmaf(pooled[g * 16 + j], Wproj[j * 32 + fo], acc);
    out[g * 32 + fo] = acc;
}

extern "C" void kernel_launch(void* const* d_in, const int* in_sizes, int n_in,
                              void* d_out, int out_size, void* d_ws, size_t ws_size,
                              hipStream_t stream) {
    const float* nf    = (const float*)d_in[0];
    const float* pos   = (const float*)d_in[1];
    const float* We    = (const float*)d_in[2];
    const float* be    = (const float*)d_in[3];
    const float* Wq    = (const float*)d_in[4];
    const float* Wk    = (const float*)d_in[5];
    const float* W1    = (const float*)d_in[6];
    const float* b1    = (const float*)d_in[7];
    const float* Wa    = (const float*)d_in[8];
    const float* Wv    = (const float*)d_in[9];
    const float* Wo    = (const float*)d_in[10];
    const float* Wproj = (const float*)d_in[11];
    const float* bproj = (const float*)d_in[12];
    const int*   ei    = (const int*)d_in[13];
    const int*   batch = (const int*)d_in[14];
    float* out = (float*)d_out;
    (void)in_sizes; (void)n_in; (void)out_size; (void)ws_size;

    float* ws     = (float*)d_ws;
    float* x      = ws;                  // 160000
    float* q      = x + 160000;          // 320000
    float* k      = q + 320000;          // 320000
    float* feat   = k + 320000;          // 160000
    float* pooled = feat + 160000;       // 256
    int*   deg    = (int*)(pooled + 256);// 10000
    float* sTau   = (float*)(deg + 10000);   // 128
    float* gT     = sTau + 128;              // 4680
    float* lgp    = gT + 4680;               // 1,920,000
    unsigned* gbu = (unsigned*)(lgp + (size_t)NN * CAP * 2);  // 7,680,000 (16B-aligned)

    hipLaunchKernelGGL(k_xqk,    dim3(625),  dim3(256), 0, stream, nf, We, be, Wq, Wk, x, q, k, (int*)pooled);
    hipLaunchKernelGGL(k_prep,   dim3(9),    dim3(256), 0, stream, W1, b1, Wa, Wv, sTau, gT);
    hipLaunchKernelGGL(k_edge,   dim3(625),  dim3(256), 0, stream, pos, ei, q, k, sTau, gT, Wo, x, deg, lgp, (uint4*)gbu);
    hipLaunchKernelGGL(k_gather, dim3(5000), dim3(256), 0, stream, deg, lgp, gbu, feat);
    hipLaunchKernelGGL(k_pool,   dim3(40),   dim3(256), 0, stream, feat, batch, pooled);
    hipLaunchKernelGGL(k_final,  dim3(1),    dim3(512), 0, stream, pooled, Wproj, bproj, out);
}